// Round 9
// baseline (256.629 us; speedup 1.0000x reference)
//
#include <hip/hip_runtime.h>

// B=16, H=W=64, C=80; tables (127,80) -> reference resize is a no-op.
// Output (B,N,N) fp32 = 1.074 GB: HBM write-stream, fill-kernel floor ~164 us.
//
// v8: TWO-KERNEL SPLIT to make the store stream fill-kernel-pure.
//  k1: v6's staging+dot phases; writes rh/rw (B*N*128 f32 = 33.5 MB) to d_ws
//      with PLAIN stores (stay L2/L3-resident).
//  k2: fill-clone writer. No LDS, no barrier, no shuffles. Per wave-token:
//      1 vf4 rw load + 16 broadcast rh scalar loads (L1-hit after first
//      touch), then 16 dependency-free nt stores of 1 KB each.
// Falls back to single-kernel v6 if ws_size < 33.5 MB.
#define HH 64
#define WW 64
#define CC 80
#define NN (HH * WW)
#define G  16
#define RPW 79
#define SP  84

typedef float vf4 __attribute__((ext_vector_type(4)));

// ---------------- kernel 1: compute rh/rw into ws ----------------
__global__ __launch_bounds__(256, 5) void relpos_dots_k1(
    const float* __restrict__ q,    // (B, N, C)
    const float* __restrict__ ph,   // (127, 80)
    const float* __restrict__ pw,   // (127, 80)
    float* __restrict__ ws)         // (B*N, 128): [0:64)=rh, [64:128)=rw
{
    __shared__ float sh_q [G * CC];     // 5.0 KB
    __shared__ float sh_pw[RPW * SP];   // 25.9 KB -> 30.9 KB, 5 blocks/CU

    const int blk = blockIdx.x;          // b*256 + hh*4 + s
    const int s   = blk & 3;
    const int hh  = (blk >> 2) & 63;
    const int b   = blk >> 8;
    const int ww0 = s * G;
    const int t   = threadIdx.x;

    const vf4* qin4 = reinterpret_cast<const vf4*>(
        q + ((size_t)b * NN + hh * 64 + ww0) * CC);
    vf4* shq4 = reinterpret_cast<vf4*>(sh_q);
    #pragma unroll
    for (int p = t; p < G * CC / 4; p += 256) shq4[p] = qin4[p];

    const vf4* pwsrc = reinterpret_cast<const vf4*>(pw + (size_t)ww0 * CC);
    vf4* shpw4 = reinterpret_cast<vf4*>(sh_pw);
    for (int p = t; p < RPW * (CC / 4); p += 256) {
        const int r  = p / 20;
        const int c4 = p % 20;
        shpw4[r * (SP / 4) + c4] = pwsrc[p];
    }
    __syncthreads();

    const int j = t & 63;
    const int w = t >> 6;
    const float* phrow = ph + (size_t)(hh + 63 - j) * CC;

    float acch[4] = {0.f, 0.f, 0.f, 0.f};
    float accw[4] = {0.f, 0.f, 0.f, 0.f};
    for (int c = 0; c < CC; c += 4) {
        vf4 hv = *reinterpret_cast<const vf4*>(phrow + c);
        #pragma unroll
        for (int k = 0; k < 4; ++k) {
            const int g = w + 4 * k;
            vf4 qv = *reinterpret_cast<const vf4*>(&sh_q[g * CC + c]);
            vf4 wv = *reinterpret_cast<const vf4*>(
                &sh_pw[(g + 63 - j) * SP + c]);
            acch[k] += qv.x * hv.x + qv.y * hv.y + qv.z * hv.z + qv.w * hv.w;
            accw[k] += qv.x * wv.x + qv.y * wv.y + qv.z * wv.z + qv.w * wv.w;
        }
    }
    // rh[j], rw[j] for token bn -> ws[bn*128 + j] / ws[bn*128 + 64 + j]
    #pragma unroll
    for (int k = 0; k < 4; ++k) {
        const int g  = w + 4 * k;
        const size_t bn = (size_t)b * NN + hh * 64 + ww0 + g;
        ws[bn * 128 + j]      = acch[k];   // plain store: keep cached
        ws[bn * 128 + 64 + j] = accw[k];
    }
}

// ---------------- kernel 2: pure streaming writer ----------------
__global__ __launch_bounds__(256) void relpos_write_k2(
    const float* __restrict__ ws,   // (B*N, 128)
    float* __restrict__ out)        // (B, N, N)
{
    const int t  = threadIdx.x;
    const int j  = t & 63;
    const int w  = t >> 6;
    const size_t bn = (size_t)blockIdx.x * 4 + w;   // one token per wave

    const float* base = ws + bn * 128;
    // rw f4 for this lane: floats 4*(j&15)..+3 of rw[64]
    const vf4 rwv = *reinterpret_cast<const vf4*>(base + 64 + 4 * (j & 15));
    // rh scalars: f4 p = it*64 + j needs rh[it*4 + (j>>4)]
    const int rhb = j >> 4;
    float rh[16];
    #pragma unroll
    for (int it = 0; it < 16; ++it) rh[it] = base[it * 4 + rhb];

    vf4* o4 = reinterpret_cast<vf4*>(out) + bn * 1024;
    #pragma unroll
    for (int it = 0; it < 16; ++it) {
        vf4 o;
        o.x = rh[it] + rwv.x; o.y = rh[it] + rwv.y;
        o.z = rh[it] + rwv.z; o.w = rh[it] + rwv.w;
        __builtin_nontemporal_store(o, &o4[it * 64 + j]);
    }
}

// ---------------- fallback: v6 single-kernel (best so far) ----------------
__global__ __launch_bounds__(256, 5) void relpos_fused_v6(
    const float* __restrict__ q, const float* __restrict__ ph,
    const float* __restrict__ pw, float* __restrict__ out)
{
    __shared__ float sh_q [G * CC];
    __shared__ float sh_pw[RPW * SP];

    const int blk = blockIdx.x;
    const int s   = blk & 3;
    const int hh  = (blk >> 2) & 63;
    const int b   = blk >> 8;
    const int ww0 = s * G;
    const int t   = threadIdx.x;

    const vf4* qin4 = reinterpret_cast<const vf4*>(
        q + ((size_t)b * NN + hh * 64 + ww0) * CC);
    vf4* shq4 = reinterpret_cast<vf4*>(sh_q);
    #pragma unroll
    for (int p = t; p < G * CC / 4; p += 256) shq4[p] = qin4[p];

    const vf4* pwsrc = reinterpret_cast<const vf4*>(pw + (size_t)ww0 * CC);
    vf4* shpw4 = reinterpret_cast<vf4*>(sh_pw);
    for (int p = t; p < RPW * (CC / 4); p += 256) {
        const int r  = p / 20;
        const int c4 = p % 20;
        shpw4[r * (SP / 4) + c4] = pwsrc[p];
    }
    __syncthreads();

    const int j = t & 63;
    const int w = t >> 6;
    const float* phrow = ph + (size_t)(hh + 63 - j) * CC;

    float acch[4] = {0.f, 0.f, 0.f, 0.f};
    float accw[4] = {0.f, 0.f, 0.f, 0.f};
    for (int c = 0; c < CC; c += 4) {
        vf4 hv = *reinterpret_cast<const vf4*>(phrow + c);
        #pragma unroll
        for (int k = 0; k < 4; ++k) {
            const int g = w + 4 * k;
            vf4 qv = *reinterpret_cast<const vf4*>(&sh_q[g * CC + c]);
            vf4 wv = *reinterpret_cast<const vf4*>(
                &sh_pw[(g + 63 - j) * SP + c]);
            acch[k] += qv.x * hv.x + qv.y * hv.y + qv.z * hv.z + qv.w * hv.w;
            accw[k] += qv.x * wv.x + qv.y * wv.y + qv.z * wv.z + qv.w * wv.w;
        }
    }

    vf4* out4 = reinterpret_cast<vf4*>(
        out + ((size_t)b * NN + hh * 64 + ww0) * NN);
    const int rwlane = 4 * (j & 15);
    const int rhbase = j >> 4;
    #pragma unroll
    for (int k = 0; k < 4; ++k) {
        const int g = w + 4 * k;
        const float w0 = __shfl(accw[k], rwlane + 0);
        const float w1 = __shfl(accw[k], rwlane + 1);
        const float w2 = __shfl(accw[k], rwlane + 2);
        const float w3 = __shfl(accw[k], rwlane + 3);
        float rh[16];
        #pragma unroll
        for (int it = 0; it < 16; ++it)
            rh[it] = __shfl(acch[k], it * 4 + rhbase);
        #pragma unroll
        for (int it = 0; it < 16; ++it) {
            vf4 o;
            o.x = rh[it] + w0; o.y = rh[it] + w1;
            o.z = rh[it] + w2; o.w = rh[it] + w3;
            __builtin_nontemporal_store(o, &out4[g * 1024 + it * 64 + j]);
        }
    }
}

extern "C" void kernel_launch(void* const* d_in, const int* in_sizes, int n_in,
                              void* d_out, int out_size, void* d_ws, size_t ws_size,
                              hipStream_t stream) {
    const float* q  = (const float*)d_in[0];
    const float* ph = (const float*)d_in[1];
    const float* pw = (const float*)d_in[2];
    float* out = (float*)d_out;

    const int B = in_sizes[0] / (NN * CC);        // 16
    const size_t need = (size_t)B * NN * 128 * sizeof(float);  // 33.5 MB

    if (ws_size >= need) {
        float* wsf = (float*)d_ws;
        relpos_dots_k1<<<dim3(B * HH * (WW / G)), 256, 0, stream>>>(q, ph, pw, wsf);
        relpos_write_k2<<<dim3(B * NN / 4), 256, 0, stream>>>(wsf, out);
    } else {
        relpos_fused_v6<<<dim3(B * HH * (WW / G)), 256, 0, stream>>>(q, ph, pw, out);
    }
}

// Round 10
// 197.876 us; speedup vs baseline: 1.2969x; 1.2969x over previous
//
#include <hip/hip_runtime.h>

// B=16, H=W=64, C=80; tables (127,80) -> reference resize is a no-op.
// Output (B,N,N) fp32 = 1.074 GB: HBM write-stream problem.
//
// FINAL (v6, best measured: 196.6 us = ~5.5 TB/s effective).
// Structure: one block per 16 tokens. Phase 1 stages q rows + the 79 needed
// pw rows into LDS (padded stride 84 -> 16B-aligned, bank-balanced b128
// reads). Phase 2 computes rh/rw dots into registers (q: LDS broadcast,
// pw: LDS gather, ph: L1-resident global gather). Phase 3 redistributes
// cross-lane via wave shuffles and issues 16 KB/token of dependency-free
// nontemporal f4 stores (nt measured +7% vs plain: keeps the 1 GB sweep
// from thrashing the read caches).
// Tested-null axes (each <=3%): barrier removal, row-persistent blocks,
// occupancy 4 vs 5 blk/CU, compute/store kernel split, plain stores.
#define HH 64
#define WW 64
#define CC 80
#define NN (HH * WW)
#define G  16          // tokens per block
#define RPW 79         // pw rows needed: ww0 .. ww0+78
#define SP  84         // padded LDS stride: 16B-aligned rows, 8 words/bank

typedef float vf4 __attribute__((ext_vector_type(4)));

__global__ __launch_bounds__(256, 5) void relpos_fused_v6(
    const float* __restrict__ q,    // (B, N, C)
    const float* __restrict__ ph,   // (127, 80)
    const float* __restrict__ pw,   // (127, 80)
    float* __restrict__ out)        // (B, N, N)
{
    __shared__ float sh_q [G * CC];     // 5.0 KB
    __shared__ float sh_pw[RPW * SP];   // 25.9 KB  -> 30.9 KB, 5 blocks/CU

    const int blk = blockIdx.x;          // b*256 + hh*4 + s
    const int s   = blk & 3;
    const int hh  = (blk >> 2) & 63;
    const int b   = blk >> 8;
    const int ww0 = s * G;
    const int t   = threadIdx.x;

    // ---- Phase 1: stage q rows + pw slice into LDS (coalesced) ----
    const vf4* qin4 = reinterpret_cast<const vf4*>(
        q + ((size_t)b * NN + hh * 64 + ww0) * CC);
    vf4* shq4 = reinterpret_cast<vf4*>(sh_q);
    #pragma unroll
    for (int p = t; p < G * CC / 4; p += 256) shq4[p] = qin4[p];

    const vf4* pwsrc = reinterpret_cast<const vf4*>(pw + (size_t)ww0 * CC);
    vf4* shpw4 = reinterpret_cast<vf4*>(sh_pw);
    for (int p = t; p < RPW * (CC / 4); p += 256) {
        const int r  = p / 20;           // row (80 floats = 20 vf4)
        const int c4 = p % 20;
        shpw4[r * (SP / 4) + c4] = pwsrc[p];
    }
    __syncthreads();

    // ---- Phase 2 (per wave): dots for tokens g = w + 4k ----
    // lane j: acch[k] = rh_g[j] = dot(q[g], ph[hh+63-j])
    //         accw[k] = rw_g[j] = dot(q[g], pw[ww0+g+63-j])
    const int j = t & 63;
    const int w = t >> 6;
    const float* phrow = ph + (size_t)(hh + 63 - j) * CC;  // L1-resident gather

    float acch[4] = {0.f, 0.f, 0.f, 0.f};
    float accw[4] = {0.f, 0.f, 0.f, 0.f};
    for (int c = 0; c < CC; c += 4) {
        vf4 hv = *reinterpret_cast<const vf4*>(phrow + c);
        #pragma unroll
        for (int k = 0; k < 4; ++k) {
            const int g = w + 4 * k;
            vf4 qv = *reinterpret_cast<const vf4*>(&sh_q[g * CC + c]);
            vf4 wv = *reinterpret_cast<const vf4*>(
                &sh_pw[(g + 63 - j) * SP + c]);
            acch[k] += qv.x * hv.x + qv.y * hv.y + qv.z * hv.z + qv.w * hv.w;
            accw[k] += qv.x * wv.x + qv.y * wv.y + qv.z * wv.z + qv.w * wv.w;
        }
    }

    // ---- Phase 3 (per wave): shuffle-to-regs, then stream nt stores ----
    // out elem m of token g: rh_g[m>>6] + rw_g[m&63].
    // vf4 p = it*64 + j: rh idx = it*4 + (j>>4); rw floats = 4*(j&15)+0..3.
    vf4* out4 = reinterpret_cast<vf4*>(
        out + ((size_t)b * NN + hh * 64 + ww0) * NN);
    const int rwlane = 4 * (j & 15);
    const int rhbase = j >> 4;
    #pragma unroll
    for (int k = 0; k < 4; ++k) {
        const int g = w + 4 * k;
        const float w0 = __shfl(accw[k], rwlane + 0);
        const float w1 = __shfl(accw[k], rwlane + 1);
        const float w2 = __shfl(accw[k], rwlane + 2);
        const float w3 = __shfl(accw[k], rwlane + 3);
        float rh[16];
        #pragma unroll
        for (int it = 0; it < 16; ++it)
            rh[it] = __shfl(acch[k], it * 4 + rhbase);
        #pragma unroll
        for (int it = 0; it < 16; ++it) {
            vf4 o;
            o.x = rh[it] + w0; o.y = rh[it] + w1;
            o.z = rh[it] + w2; o.w = rh[it] + w3;
            __builtin_nontemporal_store(o, &out4[g * 1024 + it * 64 + j]);
        }
    }
}

extern "C" void kernel_launch(void* const* d_in, const int* in_sizes, int n_in,
                              void* d_out, int out_size, void* d_ws, size_t ws_size,
                              hipStream_t stream) {
    const float* q  = (const float*)d_in[0];
    const float* ph = (const float*)d_in[1];
    const float* pw = (const float*)d_in[2];
    float* out = (float*)d_out;

    const int B = in_sizes[0] / (NN * CC);        // 16
    dim3 grid(B * HH * (WW / G));                  // 4096 blocks
    relpos_fused_v6<<<grid, 256, 0, stream>>>(q, ph, pw, out);
}